// Round 4
// baseline (109.154 us; speedup 1.0000x reference)
//
#include <hip/hip_runtime.h>
#include <hip/hip_bf16.h>
#include <stdint.h>

// Problem constants (fixed by setup_inputs): B=2, C=256, H=W=64, dg=4, K=3x3.
#define HW   4096
#define NB   2

typedef float f32x4 __attribute__((ext_vector_type(4)));
typedef short s16x8 __attribute__((ext_vector_type(8)));

__device__ __forceinline__ unsigned short f2bf(float f) {
    // round-to-nearest-even f32 -> bf16
    union { float f; unsigned int u; } v; v.f = f;
    unsigned int u = v.u;
    unsigned int r = (u + 0x7FFFu + ((u >> 16) & 1u)) >> 16;
    return (unsigned short)r;
}

__device__ __forceinline__ float bf2f(unsigned short u) {
    union { unsigned int u; float f; } v; v.u = ((unsigned int)u) << 16;
    return v.f;
}

// ---------------------------------------------------------------------------
// K_prep: the three independent prep stages in ONE dispatch (they were
// stream-serialized in graph capture; merged they run concurrently).
//   blocks [0,1152)        : offset 1x1 conv + bilinear setup (wbuf/ibuf)
//   blocks [1152,2176)     : NCHW f32 -> NHWC bf16 transpose  (fbuf)
//   blocks [2176,2752)     : weights -> bf16 MFMA A-frag order (wfrag)
// ---------------------------------------------------------------------------
__global__ void __launch_bounds__(256)
k_prep(const float* __restrict__ pred, const float* __restrict__ wo,
       const float* __restrict__ regf, const float* __restrict__ clsf,
       const float* __restrict__ wr,   const float* __restrict__ wc,
       float4* __restrict__ wbuf, int4* __restrict__ ibuf,
       unsigned short* __restrict__ fbuf, unsigned short* __restrict__ wfrag) {
    int bb = blockIdx.x;
    if (bb < 1152) {
        // ---- params: loc = ((b*9+k)*4+g)*4096 + p ----
        int loc = bb * 256 + threadIdx.x;
        int p  = loc & 4095;
        int g  = (loc >> 12) & 3;
        int bk = loc >> 14;
        int b  = bk / 9;
        int k  = bk - b * 9;
        int rowy = ((g * 9 + k) * 2) * 34;
        float oy = 0.f, ox = 0.f;
        const float* pb = pred + (size_t)b * 34 * HW + p;
        #pragma unroll
        for (int c = 0; c < 34; ++c) {
            float pv = pb[c * HW];
            oy += wo[rowy + c]      * pv;
            ox += wo[rowy + 34 + c] * pv;
        }
        int h = p >> 6, w = p & 63;
        int ky = k / 3, kx = k - ky * 3;
        float py = oy + (float)(h + ky - 1);
        float px = ox + (float)(w + kx - 1);
        float fy0 = floorf(py), fx0 = floorf(px);
        int y0 = (int)fy0, x0 = (int)fx0;
        float fy = py - fy0, fx = px - fx0;
        float wy0 = 1.f - fy, wy1 = fy, wx0 = 1.f - fx, wx1 = fx;
        if (!(y0 >= 0  && y0 <= 63)) wy0 = 0.f;
        if (!(y0 >= -1 && y0 <= 62)) wy1 = 0.f;
        if (!(x0 >= 0  && x0 <= 63)) wx0 = 0.f;
        if (!(x0 >= -1 && x0 <= 62)) wx1 = 0.f;
        int cy0 = min(max(y0, 0), 63),     cy1 = min(max(y0 + 1, 0), 63);
        int cx0 = min(max(x0, 0), 63),     cx1 = min(max(x0 + 1, 0), 63);
        wbuf[loc] = make_float4(wy0 * wx0, wy0 * wx1, wy1 * wx0, wy1 * wx1);
        ibuf[loc] = make_int4((cy0 * 64 + cx0) << 9, (cy0 * 64 + cx1) << 9,
                              (cy1 * 64 + cx0) << 9, (cy1 * 64 + cx1) << 9);
    } else if (bb < 2176) {
        // ---- NCHW f32 -> NHWC bf16 ----
        __shared__ float tile[64][65];
        int bid = bb - 1152;
        int pt = bid & 63;
        int cb = (bid >> 6) & 3;
        int b  = (bid >> 8) & 1;
        int cv = bid >> 9;
        const float* src = cv ? clsf : regf;
        int t = threadIdx.x;
        int pl = t & 63, q = t >> 6;
        #pragma unroll
        for (int i = 0; i < 16; ++i) {
            int cl = q + i * 4;
            tile[cl][pl] = src[((size_t)(b * 256 + cb * 64 + cl)) * HW + pt * 64 + pl];
        }
        __syncthreads();
        int cpair = t & 31, prow = t >> 5;
        #pragma unroll
        for (int i = 0; i < 8; ++i) {
            int p = i * 8 + prow;
            unsigned int u0 = f2bf(tile[cpair * 2][p]);
            unsigned int u1 = f2bf(tile[cpair * 2 + 1][p]);
            *(unsigned int*)&fbuf[((size_t)((cv * 2 + b) * HW + pt * 64 + p)) * 256
                                  + cb * 64 + cpair * 2] = u0 | (u1 << 16);
        }
    } else {
        // ---- weights -> A-frag: L = conv*73728 + ((s*2+kk)*16+ot)*64+lane ----
        int L = (bb - 2176) * 256 + threadIdx.x;
        int conv = L / 73728;
        int r = L - conv * 73728;
        int lane = r & 63;
        int ot = (r >> 6) & 15;
        int kk = (r >> 10) & 1;
        int s  = r >> 11;
        int k = s >> 2, g = s & 3;
        int o  = ot * 16 + (lane & 15);
        int cb = kk * 32 + (lane >> 4) * 8;
        const float* w = conv ? wc : wr;
        s16x8 v;
        #pragma unroll
        for (int j = 0; j < 8; ++j) {
            int c = cb + j;
            v[j] = (short)f2bf(w[((size_t)o * 256 + g * 64 + c) * 9 + k]);
        }
        *(s16x8*)(wfrag + (size_t)L * 8) = v;
    }
}

// ---------------------------------------------------------------------------
// K_main: fused implicit GEMM. Block = (conv,b,32-pixel tile) x 256 Cout.
// 512 blocks x 256 threads (4 waves) -> 3-4 blocks/CU co-resident (TLP hides
// the per-step barrier). Wave wo covers 64 Cout x 32 px (acc[4][2]).
// Build lanes: px = tid>>3 (0..31), cg = tid&7 -> per (pixel,corner) 8 lanes
// read a CONTIGUOUS 128B channel block (1 cache line).
// Pipeline: gathers(s+1)+params(s+2) issued before a raw s_barrier (only
// lgkmcnt drained -> vmcnt stays in flight); MFMA(s); lerp/pack/write(s+1).
// ---------------------------------------------------------------------------
__global__ void __launch_bounds__(256)
k_main(const float4* __restrict__ wbuf, const int4* __restrict__ ibuf,
       const unsigned short* __restrict__ fbuf, const unsigned short* __restrict__ wfrag,
       float* __restrict__ out) {
    __shared__ __align__(16) unsigned short vt[2][32][72];   // 32 px x 64 ch + pad

    int bid0 = blockIdx.x;
    int bid = (bid0 & 7) * 64 + (bid0 >> 3);       // XCD-contiguous swizzle (512%8==0)
    int conv = bid >> 8;
    int b    = (bid >> 7) & 1;
    int pt   = bid & 127;
    int p0   = pt * 32;

    int tid  = threadIdx.x;
    int lane = tid & 63;
    int wo   = tid >> 6;                           // wave id = Cout group (4 x 64)
    int px   = tid >> 3;                           // build: pixel 0..31
    int cg   = tid & 7;                            // build: channel granule (8 ch)

    const char* fbb = (const char*)(fbuf + (size_t)(conv * 2 + b) * HW * 256);
    const unsigned short* wfc = wfrag + (size_t)conv * 73728 * 8;

    f32x4 acc[4][2];
    #pragma unroll
    for (int i = 0; i < 4; ++i)
        #pragma unroll
        for (int j = 0; j < 2; ++j)
            acc[i][j] = (f32x4){0.f, 0.f, 0.f, 0.f};

    struct Par { float4 w4; int4 io; };
    struct Gat { s16x8 a, b, c, d; };

    auto ldpar = [&](int s) -> Par {
        int k = s >> 2, g = s & 3;
        int pidx = ((b * 9 + k) * 4 + g) * HW + p0 + px;
        Par P; P.w4 = wbuf[pidx]; P.io = ibuf[pidx];
        return P;
    };

    auto gather = [&](const Par& P, int g) -> Gat {
        const char* base = fbb + g * 128 + cg * 16;
        Gat G;
        G.a = *(const s16x8*)(base + P.io.x);
        G.b = *(const s16x8*)(base + P.io.y);
        G.c = *(const s16x8*)(base + P.io.z);
        G.d = *(const s16x8*)(base + P.io.w);
        return G;
    };

    auto finish = [&](const Par& P, const Gat& G, int buf) {
        float r[8];
        #pragma unroll
        for (int j = 0; j < 8; ++j) {
            r[j] = P.w4.x * bf2f((unsigned short)G.a[j])
                 + P.w4.y * bf2f((unsigned short)G.b[j])
                 + P.w4.z * bf2f((unsigned short)G.c[j])
                 + P.w4.w * bf2f((unsigned short)G.d[j]);
        }
        s16x8 pk;
        #pragma unroll
        for (int j = 0; j < 8; ++j) pk[j] = (short)f2bf(r[j]);
        *(s16x8*)&vt[buf][px][cg * 8] = pk;
    };

    auto domfma = [&](int s) {
        const unsigned short* wfs = wfc + (size_t)s * 2048 * 8;
        __builtin_amdgcn_s_setprio(1);
        #pragma unroll
        for (int kk = 0; kk < 2; ++kk) {
            s16x8 bfr[2];
            #pragma unroll
            for (int np = 0; np < 2; ++np)
                bfr[np] = *(const s16x8*)
                    &vt[s & 1][np * 16 + (lane & 15)][kk * 32 + (lane >> 4) * 8];
            #pragma unroll
            for (int mo = 0; mo < 4; ++mo) {
                s16x8 afr = *(const s16x8*)
                    (wfs + ((size_t)(kk * 16 + wo * 4 + mo) * 64 + lane) * 8);
                #pragma unroll
                for (int np = 0; np < 2; ++np)
                    acc[mo][np] = __builtin_amdgcn_mfma_f32_16x16x32_bf16(
                        afr, bfr[np], acc[mo][np], 0, 0, 0);
            }
        }
        __builtin_amdgcn_s_setprio(0);
    };

    // ---- software pipeline ----
    Par pc = ldpar(0);
    Par pn = ldpar(1);
    Gat gc = gather(pc, 0);
    finish(pc, gc, 0);                  // vt[0]

    for (int s = 0; s < 36; ++s) {
        Gat gn;
        Par p2 = pn;
        bool hasn = (s + 1 < 36);
        if (hasn)        gn = gather(pn, (s + 1) & 3);   // in flight across barrier
        if (s + 2 < 36)  p2 = ldpar(s + 2);
        asm volatile("s_waitcnt lgkmcnt(0)" ::: "memory"); // LDS writes visible
        __builtin_amdgcn_s_barrier();                      // vmcnt NOT drained
        domfma(s);
        if (hasn) finish(pn, gn, (s + 1) & 1);
        pn = p2;
    }

    // epilogue: C/D layout col = lane&15 (pixel), row = (lane>>4)*4 + reg (o)
    float* ob = out + (size_t)conv * (NB * 256 * HW) + (size_t)b * 256 * HW;
    #pragma unroll
    for (int mo = 0; mo < 4; ++mo)
        #pragma unroll
        for (int np = 0; np < 2; ++np)
            #pragma unroll
            for (int r = 0; r < 4; ++r) {
                int o = wo * 64 + mo * 16 + (lane >> 4) * 4 + r;
                int p = p0 + np * 16 + (lane & 15);
                float v = acc[mo][np][r];
                ob[(size_t)o * HW + p] = v > 0.f ? v : 0.f;
            }
}

// ---------------------------------------------------------------------------
// ws layout (bytes):
//   [0,        4718592)  wbuf  : 294912 float4
//   [4718592,  9437184)  ibuf  : 294912 int4
//   [9437184, 17825792)  fbuf  : 4*4096*256 bf16 NHWC
//   [17825792,20185088)  wfrag : 2*73728*8 bf16
// requires ws_size >= 20185088
// ---------------------------------------------------------------------------
extern "C" void kernel_launch(void* const* d_in, const int* in_sizes, int n_in,
                              void* d_out, int out_size, void* d_ws, size_t ws_size,
                              hipStream_t stream) {
    (void)in_sizes; (void)n_in; (void)out_size; (void)ws_size;
    const float* reg_feat = (const float*)d_in[0];
    const float* cls_feat = (const float*)d_in[1];
    const float* pred     = (const float*)d_in[2];
    const float* w_off    = (const float*)d_in[3];
    const float* w_reg    = (const float*)d_in[4];
    const float* w_cls    = (const float*)d_in[5];
    float* out = (float*)d_out;
    char* ws = (char*)d_ws;
    float4*         wbuf  = (float4*)ws;
    int4*           ibuf  = (int4*)(ws + 4718592);
    unsigned short* fbuf  = (unsigned short*)(ws + 9437184);
    unsigned short* wfrag = (unsigned short*)(ws + 17825792);

    k_prep<<<2752, 256, 0, stream>>>(pred, w_off, reg_feat, cls_feat, w_reg, w_cls,
                                     wbuf, ibuf, fbuf, wfrag);
    k_main<<< 512, 256, 0, stream>>>(wbuf, ibuf, fbuf, wfrag, out);
}

// Round 5
// 52.463 us; speedup vs baseline: 2.0806x; 2.0806x over previous
//
#include <hip/hip_runtime.h>
#include <hip/hip_bf16.h>
#include <stdint.h>

// Problem constants (fixed by setup_inputs): B=2, C=256, H=W=64, dg=4, K=3x3.
#define HW   4096
#define NB   2

typedef float f32x4 __attribute__((ext_vector_type(4)));
typedef short s16x8 __attribute__((ext_vector_type(8)));

__device__ __forceinline__ unsigned short f2bf(float f) {
    // round-to-nearest-even f32 -> bf16
    union { float f; unsigned int u; } v; v.f = f;
    unsigned int u = v.u;
    unsigned int r = (u + 0x7FFFu + ((u >> 16) & 1u)) >> 16;
    return (unsigned short)r;
}

__device__ __forceinline__ float bf2f(unsigned short u) {
    union { unsigned int u; float f; } v; v.u = ((unsigned int)u) << 16;
    return v.f;
}

// ---------------------------------------------------------------------------
// K_prep: the three independent prep stages in ONE dispatch.
//   blocks [0,1152)        : offset 1x1 conv + bilinear setup (wbuf/ibuf)
//   blocks [1152,2176)     : NCHW f32 -> NHWC bf16 transpose  (fbuf)
//   blocks [2176,2752)     : weights -> bf16 MFMA A-frag order (wfrag)
// ---------------------------------------------------------------------------
__global__ void __launch_bounds__(256)
k_prep(const float* __restrict__ pred, const float* __restrict__ wo,
       const float* __restrict__ regf, const float* __restrict__ clsf,
       const float* __restrict__ wr,   const float* __restrict__ wc,
       float4* __restrict__ wbuf, int4* __restrict__ ibuf,
       unsigned short* __restrict__ fbuf, unsigned short* __restrict__ wfrag) {
    int bb = blockIdx.x;
    if (bb < 1152) {
        // ---- params: loc = ((b*9+k)*4+g)*4096 + p ----
        int loc = bb * 256 + threadIdx.x;
        int p  = loc & 4095;
        int g  = (loc >> 12) & 3;
        int bk = loc >> 14;
        int b  = bk / 9;
        int k  = bk - b * 9;
        int rowy = ((g * 9 + k) * 2) * 34;
        float oy = 0.f, ox = 0.f;
        const float* pb = pred + (size_t)b * 34 * HW + p;
        #pragma unroll
        for (int c = 0; c < 34; ++c) {
            float pv = pb[c * HW];
            oy += wo[rowy + c]      * pv;
            ox += wo[rowy + 34 + c] * pv;
        }
        int h = p >> 6, w = p & 63;
        int ky = k / 3, kx = k - ky * 3;
        float py = oy + (float)(h + ky - 1);
        float px = ox + (float)(w + kx - 1);
        float fy0 = floorf(py), fx0 = floorf(px);
        int y0 = (int)fy0, x0 = (int)fx0;
        float fy = py - fy0, fx = px - fx0;
        float wy0 = 1.f - fy, wy1 = fy, wx0 = 1.f - fx, wx1 = fx;
        if (!(y0 >= 0  && y0 <= 63)) wy0 = 0.f;
        if (!(y0 >= -1 && y0 <= 62)) wy1 = 0.f;
        if (!(x0 >= 0  && x0 <= 63)) wx0 = 0.f;
        if (!(x0 >= -1 && x0 <= 62)) wx1 = 0.f;
        int cy0 = min(max(y0, 0), 63),     cy1 = min(max(y0 + 1, 0), 63);
        int cx0 = min(max(x0, 0), 63),     cx1 = min(max(x0 + 1, 0), 63);
        wbuf[loc] = make_float4(wy0 * wx0, wy0 * wx1, wy1 * wx0, wy1 * wx1);
        ibuf[loc] = make_int4((cy0 * 64 + cx0) << 9, (cy0 * 64 + cx1) << 9,
                              (cy1 * 64 + cx0) << 9, (cy1 * 64 + cx1) << 9);
    } else if (bb < 2176) {
        // ---- NCHW f32 -> NHWC bf16 ----
        __shared__ float tile[64][65];
        int bid = bb - 1152;
        int pt = bid & 63;
        int cb = (bid >> 6) & 3;
        int b  = (bid >> 8) & 1;
        int cv = bid >> 9;
        const float* src = cv ? clsf : regf;
        int t = threadIdx.x;
        int pl = t & 63, q = t >> 6;
        #pragma unroll
        for (int i = 0; i < 16; ++i) {
            int cl = q + i * 4;
            tile[cl][pl] = src[((size_t)(b * 256 + cb * 64 + cl)) * HW + pt * 64 + pl];
        }
        __syncthreads();
        int cpair = t & 31, prow = t >> 5;
        #pragma unroll
        for (int i = 0; i < 8; ++i) {
            int p = i * 8 + prow;
            unsigned int u0 = f2bf(tile[cpair * 2][p]);
            unsigned int u1 = f2bf(tile[cpair * 2 + 1][p]);
            *(unsigned int*)&fbuf[((size_t)((cv * 2 + b) * HW + pt * 64 + p)) * 256
                                  + cb * 64 + cpair * 2] = u0 | (u1 << 16);
        }
    } else {
        // ---- weights -> A-frag: L = conv*73728 + ((s*2+kk)*16+ot)*64+lane ----
        int L = (bb - 2176) * 256 + threadIdx.x;
        int conv = L / 73728;
        int r = L - conv * 73728;
        int lane = r & 63;
        int ot = (r >> 6) & 15;
        int kk = (r >> 10) & 1;
        int s  = r >> 11;
        int k = s >> 2, g = s & 3;
        int o  = ot * 16 + (lane & 15);
        int cb = kk * 32 + (lane >> 4) * 8;
        const float* w = conv ? wc : wr;
        s16x8 v;
        #pragma unroll
        for (int j = 0; j < 8; ++j) {
            int c = cb + j;
            v[j] = (short)f2bf(w[((size_t)o * 256 + g * 64 + c) * 9 + k]);
        }
        *(s16x8*)(wfrag + (size_t)L * 8) = v;
    }
}

// ---------------------------------------------------------------------------
// K_main: fused implicit GEMM. Block = (conv,b,64-pixel tile) x 256 Cout.
// 256 blocks x 512 threads (8 waves, 1 block/CU). Wave wo: 32 Cout x 64 px
// (acc[2][4]). R5 change vs R3: A-fragments register-double-buffered --
// loadA(s+1) issued after domfma(s), consumed after the next barrier, so
// domfma is pure LDS+MFMA (no L2 latency on the critical path).
// __launch_bounds__(512,2) raises the VGPR cap to 256 for the prefetch regs.
// ---------------------------------------------------------------------------
__global__ void __launch_bounds__(512, 2)
k_main(const float4* __restrict__ wbuf, const int4* __restrict__ ibuf,
       const unsigned short* __restrict__ fbuf, const unsigned short* __restrict__ wfrag,
       float* __restrict__ out) {
    __shared__ __align__(16) unsigned short vt[2][64][72];   // 64 px x 64 ch + pad

    int bid0 = blockIdx.x;
    int bid = (bid0 & 7) * 32 + (bid0 >> 3);       // XCD-contiguous swizzle (256%8==0)
    int conv = bid >> 7;
    int b    = (bid >> 6) & 1;
    int pt   = bid & 63;
    int p0   = pt * 64;

    int tid  = threadIdx.x;
    int lane = tid & 63;
    int wo   = tid >> 6;                           // wave id = Cout group (8 x 32)
    int px   = tid >> 3;                           // build: pixel 0..63
    int cg   = tid & 7;                            // build: channel granule (8 ch)

    const char* fbb = (const char*)(fbuf + (size_t)(conv * 2 + b) * HW * 256);
    const unsigned short* wfc = wfrag + (size_t)conv * 73728 * 8;

    f32x4 acc[2][4];
    #pragma unroll
    for (int i = 0; i < 2; ++i)
        #pragma unroll
        for (int j = 0; j < 4; ++j)
            acc[i][j] = (f32x4){0.f, 0.f, 0.f, 0.f};

    struct Par { float4 w4; int4 io; };
    struct Gat { s16x8 a, b, c, d; };

    auto ldpar = [&](int s) -> Par {
        int k = s >> 2, g = s & 3;
        int pidx = ((b * 9 + k) * 4 + g) * HW + p0 + px;
        Par P; P.w4 = wbuf[pidx]; P.io = ibuf[pidx];
        return P;
    };

    auto gather = [&](const Par& P, int g) -> Gat {
        const char* base = fbb + g * 128 + cg * 16;
        Gat G;
        G.a = *(const s16x8*)(base + P.io.x);
        G.b = *(const s16x8*)(base + P.io.y);
        G.c = *(const s16x8*)(base + P.io.z);
        G.d = *(const s16x8*)(base + P.io.w);
        return G;
    };

    auto finish = [&](const Par& P, const Gat& G, int buf) {
        float r[8];
        #pragma unroll
        for (int j = 0; j < 8; ++j) {
            r[j] = P.w4.x * bf2f((unsigned short)G.a[j])
                 + P.w4.y * bf2f((unsigned short)G.b[j])
                 + P.w4.z * bf2f((unsigned short)G.c[j])
                 + P.w4.w * bf2f((unsigned short)G.d[j]);
        }
        s16x8 pk;
        #pragma unroll
        for (int j = 0; j < 8; ++j) pk[j] = (short)f2bf(r[j]);
        *(s16x8*)&vt[buf][px][cg * 8] = pk;
    };

    // A-fragment register double-buffer: 4 frags per wave per step.
    s16x8 af00, af01, af10, af11;      // af[kk][mo]
    auto loadA = [&](int s) {
        const unsigned short* wfs = wfc + (size_t)s * 2048 * 8;
        af00 = *(const s16x8*)(wfs + ((size_t)( 0 + wo * 2 + 0) * 64 + lane) * 8);
        af01 = *(const s16x8*)(wfs + ((size_t)( 0 + wo * 2 + 1) * 64 + lane) * 8);
        af10 = *(const s16x8*)(wfs + ((size_t)(16 + wo * 2 + 0) * 64 + lane) * 8);
        af11 = *(const s16x8*)(wfs + ((size_t)(16 + wo * 2 + 1) * 64 + lane) * 8);
    };

    auto domfma = [&](int s) {
        s16x8 bfr[4];
        #pragma unroll
        for (int np = 0; np < 4; ++np)
            bfr[np] = *(const s16x8*)
                &vt[s & 1][np * 16 + (lane & 15)][(lane >> 4) * 8];          // kk=0
        #pragma unroll
        for (int np = 0; np < 4; ++np)
            acc[0][np] = __builtin_amdgcn_mfma_f32_16x16x32_bf16(af00, bfr[np],
                                                                 acc[0][np], 0, 0, 0);
        #pragma unroll
        for (int np = 0; np < 4; ++np)
            acc[1][np] = __builtin_amdgcn_mfma_f32_16x16x32_bf16(af01, bfr[np],
                                                                 acc[1][np], 0, 0, 0);
        #pragma unroll
        for (int np = 0; np < 4; ++np)
            bfr[np] = *(const s16x8*)
                &vt[s & 1][np * 16 + (lane & 15)][32 + (lane >> 4) * 8];     // kk=1
        #pragma unroll
        for (int np = 0; np < 4; ++np)
            acc[0][np] = __builtin_amdgcn_mfma_f32_16x16x32_bf16(af10, bfr[np],
                                                                 acc[0][np], 0, 0, 0);
        #pragma unroll
        for (int np = 0; np < 4; ++np)
            acc[1][np] = __builtin_amdgcn_mfma_f32_16x16x32_bf16(af11, bfr[np],
                                                                 acc[1][np], 0, 0, 0);
    };

    // ---- software pipeline ----
    loadA(0);
    Par pc = ldpar(0);
    Par pn = ldpar(1);
    Gat gc = gather(pc, 0);
    finish(pc, gc, 0);                  // vt[0]

    for (int s = 0; s < 36; ++s) {
        Gat gn;
        Par p2 = pn;
        bool hasn = (s + 1 < 36);
        if (hasn)        gn = gather(pn, (s + 1) & 3);   // in flight across barrier
        if (s + 2 < 36)  p2 = ldpar(s + 2);
        asm volatile("s_waitcnt lgkmcnt(0)" ::: "memory"); // LDS writes visible
        __builtin_amdgcn_s_barrier();                      // vmcnt NOT drained
        domfma(s);                       // pure LDS + MFMA (af prefetched)
        if (hasn) {
            loadA(s + 1);                // lands during finish + next gather phase
            finish(pn, gn, (s + 1) & 1);
        }
        pn = p2;
    }

    // epilogue: C/D layout col = lane&15 (pixel), row = (lane>>4)*4 + reg (o)
    float* ob = out + (size_t)conv * (NB * 256 * HW) + (size_t)b * 256 * HW;
    #pragma unroll
    for (int mo = 0; mo < 2; ++mo)
        #pragma unroll
        for (int np = 0; np < 4; ++np)
            #pragma unroll
            for (int r = 0; r < 4; ++r) {
                int o = wo * 32 + mo * 16 + (lane >> 4) * 4 + r;
                int p = p0 + np * 16 + (lane & 15);
                float v = acc[mo][np][r];
                ob[(size_t)o * HW + p] = v > 0.f ? v : 0.f;
            }
}

// ---------------------------------------------------------------------------
// ws layout (bytes):
//   [0,        4718592)  wbuf  : 294912 float4
//   [4718592,  9437184)  ibuf  : 294912 int4
//   [9437184, 17825792)  fbuf  : 4*4096*256 bf16 NHWC
//   [17825792,20185088)  wfrag : 2*73728*8 bf16
// requires ws_size >= 20185088
// ---------------------------------------------------------------------------
extern "C" void kernel_launch(void* const* d_in, const int* in_sizes, int n_in,
                              void* d_out, int out_size, void* d_ws, size_t ws_size,
                              hipStream_t stream) {
    (void)in_sizes; (void)n_in; (void)out_size; (void)ws_size;
    const float* reg_feat = (const float*)d_in[0];
    const float* cls_feat = (const float*)d_in[1];
    const float* pred     = (const float*)d_in[2];
    const float* w_off    = (const float*)d_in[3];
    const float* w_reg    = (const float*)d_in[4];
    const float* w_cls    = (const float*)d_in[5];
    float* out = (float*)d_out;
    char* ws = (char*)d_ws;
    float4*         wbuf  = (float4*)ws;
    int4*           ibuf  = (int4*)(ws + 4718592);
    unsigned short* fbuf  = (unsigned short*)(ws + 9437184);
    unsigned short* wfrag = (unsigned short*)(ws + 17825792);

    k_prep<<<2752, 256, 0, stream>>>(pred, w_off, reg_feat, cls_feat, w_reg, w_cls,
                                     wbuf, ibuf, fbuf, wfrag);
    k_main<<< 256, 512, 0, stream>>>(wbuf, ibuf, fbuf, wfrag, out);
}